// Round 7
// baseline (379.979 us; speedup 1.0000x reference)
//
#include <hip/hip_runtime.h>
#include <math.h>

#define N_NODES 50000
#define M_PAD   50048    // 391 * 128
#define E_EDGES 800000
#define IN_CH   128
#define C_CH    32
#define H_HEADS 8
#define HC      256      // H_HEADS * C_CH
#define BN_EPS  1e-5f
#define SLOPE   0.2f
#define LOG2E   1.44269504f

#define SCAN_CHUNK 512
#define SCAN_B     ((N_NODES + SCAN_CHUNK - 1) / SCAN_CHUNK)   // 98

typedef _Float16 f16x8 __attribute__((ext_vector_type(8)));
typedef _Float16 f16x4 __attribute__((ext_vector_type(4)));
typedef _Float16 f16x2 __attribute__((ext_vector_type(2)));
typedef float    f32x4 __attribute__((ext_vector_type(4)));

#if __has_builtin(__builtin_amdgcn_exp2f)
#define EXP2F(x) __builtin_amdgcn_exp2f(x)
#else
#define EXP2F(x) exp2f(x)
#endif

// ---------------- CSR build ----------------

__global__ void k_hist(const int* __restrict__ dst, int* deg, int e) {
    int i = blockIdx.x * blockDim.x + threadIdx.x;
    if (i < e) atomicAdd(&deg[dst[i]], 1);
}

// hierarchical scan, stage 1: per-chunk (512 elems) exclusive scan + chunk sum
__global__ __launch_bounds__(256) void k_scan_local(
        const int* __restrict__ deg, int* __restrict__ row_ptr,
        int* __restrict__ partials, int n) {
    __shared__ int sm[256];
    int t = threadIdx.x;
    int base = blockIdx.x * SCAN_CHUNK;
    int i0 = base + 2 * t, i1 = i0 + 1;
    int a = (i0 < n) ? deg[i0] : 0;
    int b = (i1 < n) ? deg[i1] : 0;
    int s = a + b;
    sm[t] = s;
    __syncthreads();
    #pragma unroll
    for (int off = 1; off < 256; off <<= 1) {
        int u = (t >= off) ? sm[t - off] : 0;
        __syncthreads();
        sm[t] += u;
        __syncthreads();
    }
    int excl = sm[t] - s;               // exclusive prefix of pair-sums
    if (i0 < n) row_ptr[i0] = excl;
    if (i1 < n) row_ptr[i1] = excl + a;
    if (t == 255) partials[blockIdx.x] = sm[255];
}

// stage 2: scan the chunk sums (SCAN_B <= 128), write total to row_ptr[n]
__global__ __launch_bounds__(128) void k_scan_part(
        int* __restrict__ partials, int* __restrict__ row_ptr_n) {
    __shared__ int sm[128];
    int t = threadIdx.x;
    int v = (t < SCAN_B) ? partials[t] : 0;
    sm[t] = v;
    __syncthreads();
    #pragma unroll
    for (int off = 1; off < 128; off <<= 1) {
        int u = (t >= off) ? sm[t - off] : 0;
        __syncthreads();
        sm[t] += u;
        __syncthreads();
    }
    if (t < SCAN_B) partials[t] = sm[t] - v;   // exclusive
    if (t == 127) *row_ptr_n = sm[127];        // total = E + N
}

// stage 3: add chunk offsets; produce row_ptr and cursor
__global__ void k_scan_add(int* __restrict__ row_ptr, int* __restrict__ cursor,
                           const int* __restrict__ partials, int n) {
    int i = blockIdx.x * blockDim.x + threadIdx.x;
    if (i < n) {
        int v = row_ptr[i] + partials[i / SCAN_CHUNK];
        row_ptr[i] = v;
        cursor[i] = v;
    }
}

// csr_src stores BYTE offsets into the xl table (node * 512) so the edge
// kernels' gather address is a single v_add.
__global__ void k_fill(const int* __restrict__ src, const int* __restrict__ dst,
                       int* cursor, int* csr_src, int e, int n) {
    int i = blockIdx.x * blockDim.x + threadIdx.x;
    if (i < e) {
        int d = dst[i];
        int p = atomicAdd(&cursor[d], 1);
        csr_src[p] = src[i] << 9;
    } else if (i < e + n) {
        int v = i - e;                  // self loop
        int p = atomicAdd(&cursor[v], 1);
        csr_src[p] = v << 9;
    }
}

// ---------------- weight prep + deg init (fused, independent elementwise) ----
// all 4 W [K,256] -> Wt f16 [256][K]; tail threads init deg[i]=1 (self-loop).

__global__ void k_split_w4(const float* __restrict__ Wl0, const float* __restrict__ Wr0,
                           const float* __restrict__ Wl1, const float* __restrict__ Wr1,
                           _Float16* __restrict__ W0lt, _Float16* __restrict__ W0rt,
                           _Float16* __restrict__ W1lt, _Float16* __restrict__ W1rt,
                           int* __restrict__ deg) {
    int t = blockIdx.x * blockDim.x + threadIdx.x;
    const float* W; _Float16* O; int K, rel;
    if (t < 32768)       { W = Wl0; O = W0lt; K = 128; rel = t; }
    else if (t < 65536)  { W = Wr0; O = W0rt; K = 128; rel = t - 32768; }
    else if (t < 131072) { W = Wl1; O = W1lt; K = 256; rel = t - 65536; }
    else if (t < 196608) { W = Wr1; O = W1rt; K = 256; rel = t - 131072; }
    else { int i = t - 196608; if (i < N_NODES) deg[i] = 1; return; }
    int n = rel / K, k = rel - n * K;
    O[rel] = (_Float16)W[(size_t)k * 256 + n];
}

// ---------------- f16 MFMA GEMM, z-fused: C0 = A@W0, C1 = A@W1 ----------------
// A staged ONCE per block, both B tables consumed (r1/r2: ~20us vs z-split).
// Tile: BM=128, BN=128, BK=32; 8 waves as 2m x 4n (8 ds_read per 16 MFMA).
// Reg-staged prefetch (T14): next K-tile's global loads issue right after the
// first barrier, flying under the MFMA block -> HBM latency hidden.
// Epilogue staged through LDS -> coalesced f16x8 stores (r4: part of -9us win).
// mfma_f32_16x16x32_f16 layouts (m89/m91-verified):
//   A: m=lane&15, k=(lane>>4)*8+j   B: n=lane&15, k=(lane>>4)*8+j
//   C/D: col=lane&15, row=(lane>>4)*4+reg

#define BK  32
#define LDA 40    // staging row pitch in f16 (32 + 8 pad -> 80 B, 16B-aligned)
#define CP  136   // C-stage pitch in f16 (272 B: 16B-aligned, quads spread banks)

__device__ __forceinline__ f16x8 cvt_h8(float4 a, float4 b) {
    f16x8 v = { (_Float16)a.x, (_Float16)a.y, (_Float16)a.z, (_Float16)a.w,
                (_Float16)b.x, (_Float16)b.y, (_Float16)b.z, (_Float16)b.w };
    return v;
}

__global__ __launch_bounds__(512) void k_gemm_mfma(
        const _Float16* __restrict__ A16, const float* __restrict__ A32,
        const _Float16* __restrict__ W0t, const _Float16* __restrict__ W1t,
        _Float16* __restrict__ C0, _Float16* __restrict__ C1, int K) {
    __shared__ _Float16 smem[128 * CP];   // 34816 B; aliases staging + C-stage
    _Float16* As  = smem;                 // 128*40 = 5120
    _Float16* Bs0 = smem + 5120;
    _Float16* Bs1 = smem + 10240;         // staging total 15360 <= 17408
    int t = threadIdx.x;
    int lane = t & 63, wv = t >> 6;           // 8 waves
    int quad = lane >> 4, r16 = lane & 15;
    int wm = wv >> 2;             // 0..1 -> row base wm*64
    int wn = wv & 3;              // 0..3 -> col base wn*32
    size_t mBase = (size_t)blockIdx.x * 128;
    size_t nBase = (size_t)blockIdx.y * 128;
    int sr = t >> 2;              // staging row 0..127
    int sc = (t & 3) * 8;         // staging col (f16 units)
    size_t rA = mBase + sr;
    const bool aValid = rA < N_NODES;
    f32x4 acc0[4][2] = {}, acc1[4][2] = {};   // [mi][ni]
    // prologue: load k0 = 0 into registers
    f16x8 pa, pb0, pb1;
    if (A32) {
        float4 a0 = {0.f, 0.f, 0.f, 0.f}, a1 = a0;
        if (aValid) {
            const float* g = A32 + rA * K + sc;
            a0 = ((const float4*)g)[0];
            a1 = ((const float4*)g)[1];
        }
        pa = cvt_h8(a0, a1);
    } else {
        pa = *(const f16x8*)(A16 + rA * K + sc);
    }
    pb0 = *(const f16x8*)(W0t + (size_t)(nBase + sr) * K + sc);
    pb1 = *(const f16x8*)(W1t + (size_t)(nBase + sr) * K + sc);
    for (int k0 = 0; k0 < K; k0 += BK) {
        *(f16x8*)&As[sr * LDA + sc]  = pa;
        *(f16x8*)&Bs0[sr * LDA + sc] = pb0;
        *(f16x8*)&Bs1[sr * LDA + sc] = pb1;
        __syncthreads();
        int kn = k0 + BK;
        if (kn < K) {                 // prefetch next tile (uniform branch)
            if (A32) {
                float4 a0 = {0.f, 0.f, 0.f, 0.f}, a1 = a0;
                if (aValid) {
                    const float* g = A32 + rA * K + kn + sc;
                    a0 = ((const float4*)g)[0];
                    a1 = ((const float4*)g)[1];
                }
                pa = cvt_h8(a0, a1);
            } else {
                pa = *(const f16x8*)(A16 + rA * K + kn + sc);
            }
            pb0 = *(const f16x8*)(W0t + (size_t)(nBase + sr) * K + kn + sc);
            pb1 = *(const f16x8*)(W1t + (size_t)(nBase + sr) * K + kn + sc);
        }
        f16x8 av[4];
        #pragma unroll
        for (int mi = 0; mi < 4; ++mi)
            av[mi] = *(f16x8*)&As[(wm * 64 + mi * 16 + r16) * LDA + quad * 8];
        #pragma unroll
        for (int ni = 0; ni < 2; ++ni) {
            f16x8 bv0 = *(f16x8*)&Bs0[(wn * 32 + ni * 16 + r16) * LDA + quad * 8];
            f16x8 bv1 = *(f16x8*)&Bs1[(wn * 32 + ni * 16 + r16) * LDA + quad * 8];
            #pragma unroll
            for (int mi = 0; mi < 4; ++mi) {
                acc0[mi][ni] = __builtin_amdgcn_mfma_f32_16x16x32_f16(av[mi], bv0, acc0[mi][ni], 0, 0, 0);
                acc1[mi][ni] = __builtin_amdgcn_mfma_f32_16x16x32_f16(av[mi], bv1, acc1[mi][ni], 0, 0, 0);
            }
        }
        __syncthreads();
    }
    // epilogue: LDS-stage each C tile, then coalesced f16x8 stores.
    int erow = t >> 2;            // 0..127
    int ec = (t & 3) * 8;         // lane-contiguous 64 B chunks across (t&3)
    size_t obase = (mBase + erow) * 256 + nBase + ec;
    #pragma unroll
    for (int tab = 0; tab < 2; ++tab) {
        __syncthreads();
        #pragma unroll
        for (int mi = 0; mi < 4; ++mi)
            #pragma unroll
            for (int ni = 0; ni < 2; ++ni)
                #pragma unroll
                for (int r = 0; r < 4; ++r) {
                    float v = tab ? acc1[mi][ni][r] : acc0[mi][ni][r];
                    smem[(wm * 64 + mi * 16 + quad * 4 + r) * CP + wn * 32 + ni * 16 + r16]
                        = (_Float16)v;
                }
        __syncthreads();
        f16x8 v0 = *(const f16x8*)&smem[erow * CP + ec];
        f16x8 v1 = *(const f16x8*)&smem[erow * CP + ec + 32];
        f16x8 v2 = *(const f16x8*)&smem[erow * CP + ec + 64];
        f16x8 v3 = *(const f16x8*)&smem[erow * CP + ec + 96];
        _Float16* C = tab ? C1 : C0;
        *(f16x8*)(C + obase)      = v0;
        *(f16x8*)(C + obase + 32) = v1;
        *(f16x8*)(C + obase + 64) = v2;
        *(f16x8*)(C + obase + 96) = v3;
    }
}

// ---------------- edge pass: one wave per node, 4 channels per lane ----------------
// Round-3 proven skeleton, main loop widened to 8 independent edge chains
// (raises ILP to cover the ~15-op serial logit chains; csr reads of 8
// contiguous indices -> s_load_dwordx8). Tail: proven 4-wide + scalar.

__device__ __forceinline__ float qreduce8(float p) {
    p += __builtin_bit_cast(float, __builtin_amdgcn_mov_dpp(
             __builtin_bit_cast(int, p), 0xB1, 0xF, 0xF, true));   // quad_perm [1,0,3,2]
    p += __builtin_bit_cast(float, __builtin_amdgcn_mov_dpp(
             __builtin_bit_cast(int, p), 0x4E, 0xF, 0xF, true));   // quad_perm [2,3,0,1]
    p += __shfl_xor(p, 4);
    return p;
}

__device__ __forceinline__ float edge_w16(f16x4 h, f16x4 xr, f16x4 att) {
    f16x4 e = h + xr;                                    // 2x v_pk_add_f16
    f16x4 es = e * (_Float16)SLOPE;                      // 2x v_pk_mul_f16
    f16x4 l = __builtin_elementwise_max(e, es);          // 2x v_pk_max_f16 (slope<1)
#if __has_builtin(__builtin_amdgcn_fdot2)
    f16x2 l01 = __builtin_shufflevector(l, l, 0, 1);
    f16x2 l23 = __builtin_shufflevector(l, l, 2, 3);
    f16x2 a01 = __builtin_shufflevector(att, att, 0, 1);
    f16x2 a23 = __builtin_shufflevector(att, att, 2, 3);
    float p = __builtin_amdgcn_fdot2(l01, a01, 0.f, false);
    p = __builtin_amdgcn_fdot2(l23, a23, p, false);
#else
    float p = (float)l[0] * (float)att[0];
    p = fmaf((float)l[1], (float)att[1], p);
    p = fmaf((float)l[2], (float)att[2], p);
    p = fmaf((float)l[3], (float)att[3], p);
#endif
    return EXP2F(qreduce8(p));         // att carries log2(e)
}

__device__ __forceinline__ void acc1e(float4& acc, f16x4 h, float w) {
    acc.x = fmaf((float)h[0], w, acc.x); acc.y = fmaf((float)h[1], w, acc.y);
    acc.z = fmaf((float)h[2], w, acc.z); acc.w = fmaf((float)h[3], w, acc.w);
}

__device__ __forceinline__ float4 edge_accum(
        const char* __restrict__ xlb, f16x4 xr_h, f16x4 att_h,
        const int* __restrict__ csr_src, int beg, int end) {
    float4 acc = {0.f, 0.f, 0.f, 0.f};
    float S = 0.f;
    int j = beg;
    for (; j + 8 <= end; j += 8) {
        int o0 = csr_src[j];     int o1 = csr_src[j + 1];
        int o2 = csr_src[j + 2]; int o3 = csr_src[j + 3];
        int o4 = csr_src[j + 4]; int o5 = csr_src[j + 5];
        int o6 = csr_src[j + 6]; int o7 = csr_src[j + 7];
        f16x4 h0 = *(const f16x4*)(xlb + o0);
        f16x4 h1 = *(const f16x4*)(xlb + o1);
        f16x4 h2 = *(const f16x4*)(xlb + o2);
        f16x4 h3 = *(const f16x4*)(xlb + o3);
        f16x4 h4 = *(const f16x4*)(xlb + o4);
        f16x4 h5 = *(const f16x4*)(xlb + o5);
        f16x4 h6 = *(const f16x4*)(xlb + o6);
        f16x4 h7 = *(const f16x4*)(xlb + o7);
        float w0 = edge_w16(h0, xr_h, att_h);
        float w1 = edge_w16(h1, xr_h, att_h);
        float w2 = edge_w16(h2, xr_h, att_h);
        float w3 = edge_w16(h3, xr_h, att_h);
        float w4 = edge_w16(h4, xr_h, att_h);
        float w5 = edge_w16(h5, xr_h, att_h);
        float w6 = edge_w16(h6, xr_h, att_h);
        float w7 = edge_w16(h7, xr_h, att_h);
        S += ((w0 + w1) + (w2 + w3)) + ((w4 + w5) + (w6 + w7));
        acc1e(acc, h0, w0); acc1e(acc, h1, w1);
        acc1e(acc, h2, w2); acc1e(acc, h3, w3);
        acc1e(acc, h4, w4); acc1e(acc, h5, w5);
        acc1e(acc, h6, w6); acc1e(acc, h7, w7);
    }
    for (; j + 4 <= end; j += 4) {
        int o0 = csr_src[j];     int o1 = csr_src[j + 1];
        int o2 = csr_src[j + 2]; int o3 = csr_src[j + 3];
        f16x4 h0 = *(const f16x4*)(xlb + o0);
        f16x4 h1 = *(const f16x4*)(xlb + o1);
        f16x4 h2 = *(const f16x4*)(xlb + o2);
        f16x4 h3 = *(const f16x4*)(xlb + o3);
        float w0 = edge_w16(h0, xr_h, att_h);
        float w1 = edge_w16(h1, xr_h, att_h);
        float w2 = edge_w16(h2, xr_h, att_h);
        float w3 = edge_w16(h3, xr_h, att_h);
        S += (w0 + w1) + (w2 + w3);
        acc1e(acc, h0, w0); acc1e(acc, h1, w1);
        acc1e(acc, h2, w2); acc1e(acc, h3, w3);
    }
    for (; j < end; ++j) {
        int o = csr_src[j];
        f16x4 hv = *(const f16x4*)(xlb + o);
        float w = edge_w16(hv, xr_h, att_h);
        S += w;
        acc1e(acc, hv, w);
    }
    float inv = 1.f / S;
    acc.x *= inv; acc.y *= inv; acc.z *= inv; acc.w *= inv;
    return acc;
}

// layer 0: concat + bias + BN + ELU -> h0 (f16).
__global__ __launch_bounds__(128) void k_edge0(
        const _Float16* __restrict__ xl, const _Float16* __restrict__ xr,
        const float* __restrict__ att,
        const int* __restrict__ row_ptr, const int* __restrict__ csr_src,
        const float* __restrict__ b0, const float* __restrict__ g0,
        const float* __restrict__ be0, const float* __restrict__ m0,
        const float* __restrict__ v0,
        _Float16* __restrict__ h0) {
    int lane = threadIdx.x & 63;
    int i = __builtin_amdgcn_readfirstlane(blockIdx.x * 2 + (threadIdx.x >> 6));
    const char* xlb = (const char*)xl + lane * 8;    // 8 B/lane within each 512 B row
    f16x4 xr_h = ((const f16x4*)xr)[(size_t)i * 64 + lane];
    float4 af = ((const float4*)att)[lane];
    f16x4 att_h = { (_Float16)(af.x * LOG2E), (_Float16)(af.y * LOG2E),
                    (_Float16)(af.z * LOG2E), (_Float16)(af.w * LOG2E) };
    int beg = row_ptr[i], end = row_ptr[i + 1];
    float4 r = edge_accum(xlb, xr_h, att_h, csr_src, beg, end);
    float4 bb = ((const float4*)b0)[lane];
    float4 gg = ((const float4*)g0)[lane];
    float4 ee = ((const float4*)be0)[lane];
    float4 mm = ((const float4*)m0)[lane];
    float4 vv = ((const float4*)v0)[lane];
    float4 o;
    o.x = (r.x + bb.x - mm.x) * rsqrtf(vv.x + BN_EPS) * gg.x + ee.x;
    o.y = (r.y + bb.y - mm.y) * rsqrtf(vv.y + BN_EPS) * gg.y + ee.y;
    o.z = (r.z + bb.z - mm.z) * rsqrtf(vv.z + BN_EPS) * gg.z + ee.z;
    o.w = (r.w + bb.w - mm.w) * rsqrtf(vv.w + BN_EPS) * gg.w + ee.w;
    o.x = o.x > 0.f ? o.x : expm1f(o.x);
    o.y = o.y > 0.f ? o.y : expm1f(o.y);
    o.z = o.z > 0.f ? o.z : expm1f(o.z);
    o.w = o.w > 0.f ? o.w : expm1f(o.w);
    f16x4 hh = { (_Float16)o.x, (_Float16)o.y, (_Float16)o.z, (_Float16)o.w };
    ((f16x4*)h0)[(size_t)i * 64 + lane] = hh;
}

// layer 1: head-mean + bias + BN + classifier, fully in-register.
__global__ __launch_bounds__(128) void k_edge1(
        const _Float16* __restrict__ xl, const _Float16* __restrict__ xr,
        const float* __restrict__ att,
        const int* __restrict__ row_ptr, const int* __restrict__ csr_src,
        const float* __restrict__ b1, const float* __restrict__ g1,
        const float* __restrict__ be1, const float* __restrict__ m1,
        const float* __restrict__ v1,
        const float* __restrict__ Wc, const float* __restrict__ bc,
        float* __restrict__ out) {
    int lane = threadIdx.x & 63;
    int q = lane & 7;
    int i = __builtin_amdgcn_readfirstlane(blockIdx.x * 2 + (threadIdx.x >> 6));
    const char* xlb = (const char*)xl + lane * 8;
    f16x4 xr_h = ((const f16x4*)xr)[(size_t)i * 64 + lane];
    float4 af = ((const float4*)att)[lane];
    f16x4 att_h = { (_Float16)(af.x * LOG2E), (_Float16)(af.y * LOG2E),
                    (_Float16)(af.z * LOG2E), (_Float16)(af.w * LOG2E) };
    int beg = row_ptr[i], end = row_ptr[i + 1];
    float4 r = edge_accum(xlb, xr_h, att_h, csr_src, beg, end);
    #pragma unroll
    for (int mask = 8; mask <= 32; mask <<= 1) {
        r.x += __shfl_xor(r.x, mask);
        r.y += __shfl_xor(r.y, mask);
        r.z += __shfl_xor(r.z, mask);
        r.w += __shfl_xor(r.w, mask);
    }
    float4 bb = ((const float4*)b1)[q];
    float4 gg = ((const float4*)g1)[q];
    float4 ee = ((const float4*)be1)[q];
    float4 mm = ((const float4*)m1)[q];
    float4 vv = ((const float4*)v1)[q];
    r.x = (r.x * 0.125f + bb.x - mm.x) * rsqrtf(vv.x + BN_EPS) * gg.x + ee.x;
    r.y = (r.y * 0.125f + bb.y - mm.y) * rsqrtf(vv.y + BN_EPS) * gg.y + ee.y;
    r.z = (r.z * 0.125f + bb.z - mm.z) * rsqrtf(vv.z + BN_EPS) * gg.z + ee.z;
    r.w = (r.w * 0.125f + bb.w - mm.w) * rsqrtf(vv.w + BN_EPS) * gg.w + ee.w;
    float4 wc0 = ((const float4*)Wc)[q * 2];
    float4 wc1 = ((const float4*)Wc)[q * 2 + 1];
    float o0 = r.x * wc0.x + r.y * wc0.z + r.z * wc1.x + r.w * wc1.z;
    float o1 = r.x * wc0.y + r.y * wc0.w + r.z * wc1.y + r.w * wc1.w;
    #pragma unroll
    for (int mask = 1; mask <= 4; mask <<= 1) {
        o0 += __shfl_xor(o0, mask);
        o1 += __shfl_xor(o1, mask);
    }
    if (lane == 0) {
        float2 ov = {o0 + bc[0], o1 + bc[1]};
        *(float2*)(out + (size_t)i * 2) = ov;
    }
}

// ---------------- launcher ----------------

extern "C" void kernel_launch(void* const* d_in, const int* in_sizes, int n_in,
                              void* d_out, int out_size, void* d_ws, size_t ws_size,
                              hipStream_t stream) {
    const float* x    = (const float*)d_in[0];
    const int*   ei   = (const int*)d_in[1];
    const float* Wl0  = (const float*)d_in[2];
    const float* Wr0  = (const float*)d_in[3];
    const float* att0 = (const float*)d_in[4];
    const float* b0   = (const float*)d_in[5];
    const float* g0   = (const float*)d_in[6];
    const float* be0  = (const float*)d_in[7];
    const float* m0   = (const float*)d_in[8];
    const float* v0   = (const float*)d_in[9];
    const float* Wl1  = (const float*)d_in[10];
    const float* Wr1  = (const float*)d_in[11];
    const float* att1 = (const float*)d_in[12];
    const float* b1   = (const float*)d_in[13];
    const float* g1   = (const float*)d_in[14];
    const float* be1  = (const float*)d_in[15];
    const float* m1   = (const float*)d_in[16];
    const float* v1   = (const float*)d_in[17];
    const float* Wc   = (const float*)d_in[18];
    const float* bc   = (const float*)d_in[19];
    float* out = (float*)d_out;

    const int N = N_NODES, E = E_EDGES;
    const int* srcp = ei;        // edge_index[0]
    const int* dstp = ei + E;    // edge_index[1]

    // workspace carve-up (16B-aligned chunks)
    char* p = (char*)d_ws;
    _Float16* xlf = (_Float16*)p; p += (size_t)M_PAD * HC * 2;   // xl table [M_PAD,256] f16
    _Float16* xrf = (_Float16*)p; p += (size_t)M_PAD * HC * 2;   // xr table [M_PAD,256] f16
    _Float16* h0  = (_Float16*)p; p += (size_t)M_PAD * HC * 2;   // h0 [M_PAD,256] f16
    _Float16* W0lt = (_Float16*)p; p += (size_t)HC * IN_CH * 2;  // Wt of Wl0 [256][128]
    _Float16* W0rt = (_Float16*)p; p += (size_t)HC * IN_CH * 2;
    _Float16* W1lt = (_Float16*)p; p += (size_t)HC * HC * 2;     // Wt of Wl1 [256][256]
    _Float16* W1rt = (_Float16*)p; p += (size_t)HC * HC * 2;
    int* deg      = (int*)p;
    int* row_ptr  = deg + N;
    int* cursor   = row_ptr + (N + 1);
    int* partials = cursor + N;
    int* csr_src  = partials + ((SCAN_B + 3) & ~3);   // E+N entries

    // weight prep + deg init (fused), then CSR build (by dst)
    k_split_w4<<<964, 256, 0, stream>>>(Wl0, Wr0, Wl1, Wr1,
                                        W0lt, W0rt, W1lt, W1rt, deg);
    k_hist<<<(E + 255) / 256, 256, 0, stream>>>(dstp, deg, E);
    k_scan_local<<<SCAN_B, 256, 0, stream>>>(deg, row_ptr, partials, N);
    k_scan_part<<<1, 128, 0, stream>>>(partials, row_ptr + N);
    k_scan_add<<<(N + 255) / 256, 256, 0, stream>>>(row_ptr, cursor, partials, N);
    k_fill<<<(E + N + 255) / 256, 256, 0, stream>>>(srcp, dstp, cursor, csr_src, E, N);

    dim3 ggrid(M_PAD / 128, 2);
    // layer 0 projections: xl0 = x@Wl0, xr0 = x@Wr0 (fused, A staged once)
    k_gemm_mfma<<<ggrid, 512, 0, stream>>>(nullptr, x, W0lt, W0rt, xlf, xrf, IN_CH);
    // layer 0 edge pass + BN + ELU -> h0 (f16)
    k_edge0<<<N / 2, 128, 0, stream>>>(xlf, xrf, att0, row_ptr, csr_src,
                                       b0, g0, be0, m0, v0, h0);
    // layer 1 projections: xl1 = h0@Wl1, xr1 = h0@Wr1
    k_gemm_mfma<<<ggrid, 512, 0, stream>>>(h0, nullptr, W1lt, W1rt, xlf, xrf, HC);
    // layer 1 edge pass + head-mean + BN + classifier -> out
    k_edge1<<<N / 2, 128, 0, stream>>>(xlf, xrf, att1, row_ptr, csr_src,
                                       b1, g1, be1, m1, v1, Wc, bc, out);
}

// Round 8
// 357.465 us; speedup vs baseline: 1.0630x; 1.0630x over previous
//
#include <hip/hip_runtime.h>
#include <math.h>

#define N_NODES 50000
#define M_PAD   50048    // 391 * 128
#define E_EDGES 800000
#define IN_CH   128
#define C_CH    32
#define H_HEADS 8
#define HC      256      // H_HEADS * C_CH
#define BN_EPS  1e-5f
#define SLOPE   0.2f
#define LOG2E   1.44269504f

#define SCAN_CHUNK 512
#define SCAN_B     ((N_NODES + SCAN_CHUNK - 1) / SCAN_CHUNK)   // 98

typedef _Float16 f16x8 __attribute__((ext_vector_type(8)));
typedef _Float16 f16x4 __attribute__((ext_vector_type(4)));
typedef _Float16 f16x2 __attribute__((ext_vector_type(2)));
typedef float    f32x4 __attribute__((ext_vector_type(4)));

#if __has_builtin(__builtin_amdgcn_exp2f)
#define EXP2F(x) __builtin_amdgcn_exp2f(x)
#else
#define EXP2F(x) exp2f(x)
#endif

// ---------------- CSR build ----------------
// deg zero-init via hipMemsetAsync; hist fused into gemm0 (y==2 blocks);
// self-loop contributes via +1 in the scan read.

// scan stage 1+2 fused: per-chunk scan; LAST finishing block scans the
// chunk sums (single-pass via atomic done-counter + fences).
__global__ __launch_bounds__(256) void k_scan_local(
        const int* __restrict__ deg, int* __restrict__ row_ptr,
        int* __restrict__ partials, int* __restrict__ done, int n) {
    __shared__ int sm[256];
    __shared__ int isLast;
    int t = threadIdx.x;
    int base = blockIdx.x * SCAN_CHUNK;
    int i0 = base + 2 * t, i1 = i0 + 1;
    int a = (i0 < n) ? deg[i0] + 1 : 0;     // +1 = self-loop
    int b = (i1 < n) ? deg[i1] + 1 : 0;
    int s = a + b;
    sm[t] = s;
    __syncthreads();
    #pragma unroll
    for (int off = 1; off < 256; off <<= 1) {
        int u = (t >= off) ? sm[t - off] : 0;
        __syncthreads();
        sm[t] += u;
        __syncthreads();
    }
    int excl = sm[t] - s;               // exclusive prefix of pair-sums
    if (i0 < n) row_ptr[i0] = excl;
    if (i1 < n) row_ptr[i1] = excl + a;
    if (t == 255) {
        partials[blockIdx.x] = sm[255];
        __threadfence();
        int r = atomicAdd(done, 1);
        isLast = (r == SCAN_B - 1);
    }
    __syncthreads();
    if (isLast) {
        __threadfence();                // acquire: see all blocks' partials
        int v = (t < SCAN_B) ? partials[t] : 0;
        __syncthreads();                // sm reuse
        sm[t] = v;
        __syncthreads();
        #pragma unroll
        for (int off = 1; off < 256; off <<= 1) {
            int u = (t >= off) ? sm[t - off] : 0;
            __syncthreads();
            sm[t] += u;
            __syncthreads();
        }
        if (t < SCAN_B) partials[t] = sm[t] - v;   // exclusive
        if (t == 255) row_ptr[n] = sm[255];        // total = E + N
    }
}

// stage 3: add chunk offsets; place self-loop; cursor starts past it.
__global__ void k_scan_add(int* __restrict__ row_ptr, int* __restrict__ cursor,
                           int* __restrict__ csr_src,
                           const int* __restrict__ partials, int n) {
    int i = blockIdx.x * blockDim.x + threadIdx.x;
    if (i < n) {
        int v = row_ptr[i] + partials[i / SCAN_CHUNK];
        row_ptr[i] = v;
        cursor[i] = v + 1;              // self-loop occupies slot v
        csr_src[v] = i << 9;            // byte offset (node * 512)
    }
}

// csr_src stores BYTE offsets into the xl table (node * 512) so the edge
// kernels' gather address is a single v_add.
__global__ void k_fill(const int* __restrict__ src, const int* __restrict__ dst,
                       int* cursor, int* csr_src, int e) {
    int i = blockIdx.x * blockDim.x + threadIdx.x;
    if (i < e) {
        int d = dst[i];
        int p = atomicAdd(&cursor[d], 1);
        csr_src[p] = src[i] << 9;
    }
}

// ---------------- weight prep + fold tables (fused elementwise) -------------
// all 4 W [K,256] -> Wt f16 [256][K]; tail 256 threads compute:
//   layer0 BN fold sc0/sh0[256], attl0 = att0*log2e (f16),
//   layer1 BN fold sc1/sh1[32] (0.125 head-mean folded), attl1 (f16).

__global__ void k_split_w4(const float* __restrict__ Wl0, const float* __restrict__ Wr0,
                           const float* __restrict__ Wl1, const float* __restrict__ Wr1,
                           _Float16* __restrict__ W0lt, _Float16* __restrict__ W0rt,
                           _Float16* __restrict__ W1lt, _Float16* __restrict__ W1rt,
                           const float* __restrict__ att0, const float* __restrict__ att1,
                           const float* __restrict__ b0, const float* __restrict__ g0,
                           const float* __restrict__ be0, const float* __restrict__ m0,
                           const float* __restrict__ v0,
                           const float* __restrict__ b1, const float* __restrict__ g1,
                           const float* __restrict__ be1, const float* __restrict__ m1,
                           const float* __restrict__ v1,
                           float* __restrict__ sc0, float* __restrict__ sh0,
                           float* __restrict__ sc1, float* __restrict__ sh1,
                           _Float16* __restrict__ attl0, _Float16* __restrict__ attl1) {
    int t = blockIdx.x * blockDim.x + threadIdx.x;
    const float* W; _Float16* O; int K, rel;
    if (t < 32768)       { W = Wl0; O = W0lt; K = 128; rel = t; }
    else if (t < 65536)  { W = Wr0; O = W0rt; K = 128; rel = t - 32768; }
    else if (t < 131072) { W = Wl1; O = W1lt; K = 256; rel = t - 65536; }
    else if (t < 196608) { W = Wr1; O = W1rt; K = 256; rel = t - 131072; }
    else {
        int ch = t - 196608;
        if (ch < 256) {
            float s = rsqrtf(v0[ch] + BN_EPS) * g0[ch];
            sc0[ch] = s;
            sh0[ch] = (b0[ch] - m0[ch]) * s + be0[ch];
            attl0[ch] = (_Float16)(att0[ch] * LOG2E);
            attl1[ch] = (_Float16)(att1[ch] * LOG2E);
            if (ch < 32) {
                float s1 = rsqrtf(v1[ch] + BN_EPS) * g1[ch];
                sc1[ch] = 0.125f * s1;
                sh1[ch] = (b1[ch] - m1[ch]) * s1 + be1[ch];
            }
        }
        return;
    }
    int n = rel / K, k = rel - n * K;
    O[rel] = (_Float16)W[(size_t)k * 256 + n];
}

// ---------------- f16 MFMA GEMM, z-fused: C0 = A@W0, C1 = A@W1 ----------------
// A staged ONCE per block, both B tables consumed (r1/r2: ~20us vs z-split).
// Tile: BM=128, BN=128, BK=32; 8 waves as 2m x 4n (8 ds_read per 16 MFMA).
// Reg-staged prefetch; LDS-staged coalesced epilogue (r4: -9us).
// blockIdx.y==2 blocks (layer-0 launch only) run the CSR degree histogram,
// overlapping its 800K atomics under the MFMA work.
// mfma_f32_16x16x32_f16 layouts (m89/m91-verified):
//   A: m=lane&15, k=(lane>>4)*8+j   B: n=lane&15, k=(lane>>4)*8+j
//   C/D: col=lane&15, row=(lane>>4)*4+reg

#define BK  32
#define LDA 40    // staging row pitch in f16 (32 + 8 pad -> 80 B, 16B-aligned)
#define CP  136   // C-stage pitch in f16 (272 B: 16B-aligned, quads spread banks)

__device__ __forceinline__ f16x8 cvt_h8(float4 a, float4 b) {
    f16x8 v = { (_Float16)a.x, (_Float16)a.y, (_Float16)a.z, (_Float16)a.w,
                (_Float16)b.x, (_Float16)b.y, (_Float16)b.z, (_Float16)b.w };
    return v;
}

__global__ __launch_bounds__(512) void k_gemm_mfma(
        const _Float16* __restrict__ A16, const float* __restrict__ A32,
        const _Float16* __restrict__ W0t, const _Float16* __restrict__ W1t,
        _Float16* __restrict__ C0, _Float16* __restrict__ C1, int K,
        const int* __restrict__ hdst, int* __restrict__ hdeg, int he) {
    if (blockIdx.y == 2) {              // fused degree histogram (layer 0 only)
        int tid = blockIdx.x * blockDim.x + threadIdx.x;
        int stride = gridDim.x * blockDim.x;
        for (int i = tid; i < he; i += stride)
            atomicAdd(&hdeg[hdst[i]], 1);
        return;
    }
    __shared__ _Float16 smem[128 * CP];   // 34816 B; aliases staging + C-stage
    _Float16* As  = smem;                 // 128*40 = 5120
    _Float16* Bs0 = smem + 5120;
    _Float16* Bs1 = smem + 10240;         // staging total 15360 <= 17408
    int t = threadIdx.x;
    int lane = t & 63, wv = t >> 6;           // 8 waves
    int quad = lane >> 4, r16 = lane & 15;
    int wm = wv >> 2;             // 0..1 -> row base wm*64
    int wn = wv & 3;              // 0..3 -> col base wn*32
    size_t mBase = (size_t)blockIdx.x * 128;
    size_t nBase = (size_t)blockIdx.y * 128;
    int sr = t >> 2;              // staging row 0..127
    int sc = (t & 3) * 8;         // staging col (f16 units)
    size_t rA = mBase + sr;
    const bool aValid = rA < N_NODES;
    f32x4 acc0[4][2] = {}, acc1[4][2] = {};   // [mi][ni]
    // prologue: load k0 = 0 into registers
    f16x8 pa, pb0, pb1;
    if (A32) {
        float4 a0 = {0.f, 0.f, 0.f, 0.f}, a1 = a0;
        if (aValid) {
            const float* g = A32 + rA * K + sc;
            a0 = ((const float4*)g)[0];
            a1 = ((const float4*)g)[1];
        }
        pa = cvt_h8(a0, a1);
    } else {
        pa = *(const f16x8*)(A16 + rA * K + sc);
    }
    pb0 = *(const f16x8*)(W0t + (size_t)(nBase + sr) * K + sc);
    pb1 = *(const f16x8*)(W1t + (size_t)(nBase + sr) * K + sc);
    for (int k0 = 0; k0 < K; k0 += BK) {
        *(f16x8*)&As[sr * LDA + sc]  = pa;
        *(f16x8*)&Bs0[sr * LDA + sc] = pb0;
        *(f16x8*)&Bs1[sr * LDA + sc] = pb1;
        __syncthreads();
        int kn = k0 + BK;
        if (kn < K) {                 // prefetch next tile (uniform branch)
            if (A32) {
                float4 a0 = {0.f, 0.f, 0.f, 0.f}, a1 = a0;
                if (aValid) {
                    const float* g = A32 + rA * K + kn + sc;
                    a0 = ((const float4*)g)[0];
                    a1 = ((const float4*)g)[1];
                }
                pa = cvt_h8(a0, a1);
            } else {
                pa = *(const f16x8*)(A16 + rA * K + kn + sc);
            }
            pb0 = *(const f16x8*)(W0t + (size_t)(nBase + sr) * K + kn + sc);
            pb1 = *(const f16x8*)(W1t + (size_t)(nBase + sr) * K + kn + sc);
        }
        f16x8 av[4];
        #pragma unroll
        for (int mi = 0; mi < 4; ++mi)
            av[mi] = *(f16x8*)&As[(wm * 64 + mi * 16 + r16) * LDA + quad * 8];
        #pragma unroll
        for (int ni = 0; ni < 2; ++ni) {
            f16x8 bv0 = *(f16x8*)&Bs0[(wn * 32 + ni * 16 + r16) * LDA + quad * 8];
            f16x8 bv1 = *(f16x8*)&Bs1[(wn * 32 + ni * 16 + r16) * LDA + quad * 8];
            #pragma unroll
            for (int mi = 0; mi < 4; ++mi) {
                acc0[mi][ni] = __builtin_amdgcn_mfma_f32_16x16x32_f16(av[mi], bv0, acc0[mi][ni], 0, 0, 0);
                acc1[mi][ni] = __builtin_amdgcn_mfma_f32_16x16x32_f16(av[mi], bv1, acc1[mi][ni], 0, 0, 0);
            }
        }
        __syncthreads();
    }
    // epilogue: LDS-stage each C tile, then coalesced f16x8 stores.
    int erow = t >> 2;            // 0..127
    int ec = (t & 3) * 8;         // lane-contiguous 64 B chunks across (t&3)
    size_t obase = (mBase + erow) * 256 + nBase + ec;
    #pragma unroll
    for (int tab = 0; tab < 2; ++tab) {
        __syncthreads();
        #pragma unroll
        for (int mi = 0; mi < 4; ++mi)
            #pragma unroll
            for (int ni = 0; ni < 2; ++ni)
                #pragma unroll
                for (int r = 0; r < 4; ++r) {
                    float v = tab ? acc1[mi][ni][r] : acc0[mi][ni][r];
                    smem[(wm * 64 + mi * 16 + quad * 4 + r) * CP + wn * 32 + ni * 16 + r16]
                        = (_Float16)v;
                }
        __syncthreads();
        f16x8 v0 = *(const f16x8*)&smem[erow * CP + ec];
        f16x8 v1 = *(const f16x8*)&smem[erow * CP + ec + 32];
        f16x8 v2 = *(const f16x8*)&smem[erow * CP + ec + 64];
        f16x8 v3 = *(const f16x8*)&smem[erow * CP + ec + 96];
        _Float16* C = tab ? C1 : C0;
        *(f16x8*)(C + obase)      = v0;
        *(f16x8*)(C + obase + 32) = v1;
        *(f16x8*)(C + obase + 64) = v2;
        *(f16x8*)(C + obase + 96) = v3;
    }
}

// ---------------- edge pass: one wave per node, 4 channels per lane ----------------
// r7 skeleton (8 + 4 + scalar edge chains); per-node setup slimmed to 3 table
// loads (precomputed BN fold + f16 att).

__device__ __forceinline__ float qreduce8(float p) {
    p += __builtin_bit_cast(float, __builtin_amdgcn_mov_dpp(
             __builtin_bit_cast(int, p), 0xB1, 0xF, 0xF, true));   // quad_perm [1,0,3,2]
    p += __builtin_bit_cast(float, __builtin_amdgcn_mov_dpp(
             __builtin_bit_cast(int, p), 0x4E, 0xF, 0xF, true));   // quad_perm [2,3,0,1]
    p += __shfl_xor(p, 4);
    return p;
}

__device__ __forceinline__ float edge_w16(f16x4 h, f16x4 xr, f16x4 att) {
    f16x4 e = h + xr;                                    // 2x v_pk_add_f16
    f16x4 es = e * (_Float16)SLOPE;                      // 2x v_pk_mul_f16
    f16x4 l = __builtin_elementwise_max(e, es);          // 2x v_pk_max_f16 (slope<1)
#if __has_builtin(__builtin_amdgcn_fdot2)
    f16x2 l01 = __builtin_shufflevector(l, l, 0, 1);
    f16x2 l23 = __builtin_shufflevector(l, l, 2, 3);
    f16x2 a01 = __builtin_shufflevector(att, att, 0, 1);
    f16x2 a23 = __builtin_shufflevector(att, att, 2, 3);
    float p = __builtin_amdgcn_fdot2(l01, a01, 0.f, false);
    p = __builtin_amdgcn_fdot2(l23, a23, p, false);
#else
    float p = (float)l[0] * (float)att[0];
    p = fmaf((float)l[1], (float)att[1], p);
    p = fmaf((float)l[2], (float)att[2], p);
    p = fmaf((float)l[3], (float)att[3], p);
#endif
    return EXP2F(qreduce8(p));         // att carries log2(e)
}

__device__ __forceinline__ void acc1e(float4& acc, f16x4 h, float w) {
    acc.x = fmaf((float)h[0], w, acc.x); acc.y = fmaf((float)h[1], w, acc.y);
    acc.z = fmaf((float)h[2], w, acc.z); acc.w = fmaf((float)h[3], w, acc.w);
}

__device__ __forceinline__ float4 edge_accum(
        const char* __restrict__ xlb, f16x4 xr_h, f16x4 att_h,
        const int* __restrict__ csr_src, int beg, int end) {
    float4 acc = {0.f, 0.f, 0.f, 0.f};
    float S = 0.f;
    int j = beg;
    for (; j + 8 <= end; j += 8) {
        int o0 = csr_src[j];     int o1 = csr_src[j + 1];
        int o2 = csr_src[j + 2]; int o3 = csr_src[j + 3];
        int o4 = csr_src[j + 4]; int o5 = csr_src[j + 5];
        int o6 = csr_src[j + 6]; int o7 = csr_src[j + 7];
        f16x4 h0 = *(const f16x4*)(xlb + o0);
        f16x4 h1 = *(const f16x4*)(xlb + o1);
        f16x4 h2 = *(const f16x4*)(xlb + o2);
        f16x4 h3 = *(const f16x4*)(xlb + o3);
        f16x4 h4 = *(const f16x4*)(xlb + o4);
        f16x4 h5 = *(const f16x4*)(xlb + o5);
        f16x4 h6 = *(const f16x4*)(xlb + o6);
        f16x4 h7 = *(const f16x4*)(xlb + o7);
        float w0 = edge_w16(h0, xr_h, att_h);
        float w1 = edge_w16(h1, xr_h, att_h);
        float w2 = edge_w16(h2, xr_h, att_h);
        float w3 = edge_w16(h3, xr_h, att_h);
        float w4 = edge_w16(h4, xr_h, att_h);
        float w5 = edge_w16(h5, xr_h, att_h);
        float w6 = edge_w16(h6, xr_h, att_h);
        float w7 = edge_w16(h7, xr_h, att_h);
        S += ((w0 + w1) + (w2 + w3)) + ((w4 + w5) + (w6 + w7));
        acc1e(acc, h0, w0); acc1e(acc, h1, w1);
        acc1e(acc, h2, w2); acc1e(acc, h3, w3);
        acc1e(acc, h4, w4); acc1e(acc, h5, w5);
        acc1e(acc, h6, w6); acc1e(acc, h7, w7);
    }
    for (; j + 4 <= end; j += 4) {
        int o0 = csr_src[j];     int o1 = csr_src[j + 1];
        int o2 = csr_src[j + 2]; int o3 = csr_src[j + 3];
        f16x4 h0 = *(const f16x4*)(xlb + o0);
        f16x4 h1 = *(const f16x4*)(xlb + o1);
        f16x4 h2 = *(const f16x4*)(xlb + o2);
        f16x4 h3 = *(const f16x4*)(xlb + o3);
        float w0 = edge_w16(h0, xr_h, att_h);
        float w1 = edge_w16(h1, xr_h, att_h);
        float w2 = edge_w16(h2, xr_h, att_h);
        float w3 = edge_w16(h3, xr_h, att_h);
        S += (w0 + w1) + (w2 + w3);
        acc1e(acc, h0, w0); acc1e(acc, h1, w1);
        acc1e(acc, h2, w2); acc1e(acc, h3, w3);
    }
    for (; j < end; ++j) {
        int o = csr_src[j];
        f16x4 hv = *(const f16x4*)(xlb + o);
        float w = edge_w16(hv, xr_h, att_h);
        S += w;
        acc1e(acc, hv, w);
    }
    float inv = 1.f / S;
    acc.x *= inv; acc.y *= inv; acc.z *= inv; acc.w *= inv;
    return acc;
}

// layer 0: concat + folded BN + ELU -> h0 (f16).
__global__ __launch_bounds__(128) void k_edge0(
        const _Float16* __restrict__ xl, const _Float16* __restrict__ xr,
        const _Float16* __restrict__ attl,
        const int* __restrict__ row_ptr, const int* __restrict__ csr_src,
        const float* __restrict__ sc0, const float* __restrict__ sh0,
        _Float16* __restrict__ h0) {
    int lane = threadIdx.x & 63;
    int i = __builtin_amdgcn_readfirstlane(blockIdx.x * 2 + (threadIdx.x >> 6));
    const char* xlb = (const char*)xl + lane * 8;    // 8 B/lane within each 512 B row
    f16x4 xr_h = ((const f16x4*)xr)[(size_t)i * 64 + lane];
    f16x4 att_h = ((const f16x4*)attl)[lane];
    int beg = row_ptr[i], end = row_ptr[i + 1];
    float4 r = edge_accum(xlb, xr_h, att_h, csr_src, beg, end);
    float4 sc = ((const float4*)sc0)[lane];
    float4 sh = ((const float4*)sh0)[lane];
    float4 o;
    o.x = r.x * sc.x + sh.x;
    o.y = r.y * sc.y + sh.y;
    o.z = r.z * sc.z + sh.z;
    o.w = r.w * sc.w + sh.w;
    o.x = o.x > 0.f ? o.x : expm1f(o.x);
    o.y = o.y > 0.f ? o.y : expm1f(o.y);
    o.z = o.z > 0.f ? o.z : expm1f(o.z);
    o.w = o.w > 0.f ? o.w : expm1f(o.w);
    f16x4 hh = { (_Float16)o.x, (_Float16)o.y, (_Float16)o.z, (_Float16)o.w };
    ((f16x4*)h0)[(size_t)i * 64 + lane] = hh;
}

// layer 1: head-mean + folded BN + classifier, fully in-register.
__global__ __launch_bounds__(128) void k_edge1(
        const _Float16* __restrict__ xl, const _Float16* __restrict__ xr,
        const _Float16* __restrict__ attl,
        const int* __restrict__ row_ptr, const int* __restrict__ csr_src,
        const float* __restrict__ sc1, const float* __restrict__ sh1,
        const float* __restrict__ Wc, const float* __restrict__ bc,
        float* __restrict__ out) {
    int lane = threadIdx.x & 63;
    int q = lane & 7;
    int i = __builtin_amdgcn_readfirstlane(blockIdx.x * 2 + (threadIdx.x >> 6));
    const char* xlb = (const char*)xl + lane * 8;
    f16x4 xr_h = ((const f16x4*)xr)[(size_t)i * 64 + lane];
    f16x4 att_h = ((const f16x4*)attl)[lane];
    int beg = row_ptr[i], end = row_ptr[i + 1];
    float4 r = edge_accum(xlb, xr_h, att_h, csr_src, beg, end);
    #pragma unroll
    for (int mask = 8; mask <= 32; mask <<= 1) {
        r.x += __shfl_xor(r.x, mask);
        r.y += __shfl_xor(r.y, mask);
        r.z += __shfl_xor(r.z, mask);
        r.w += __shfl_xor(r.w, mask);
    }
    float4 sA = ((const float4*)sc1)[q];   // 0.125 * rsqrt * g
    float4 sB = ((const float4*)sh1)[q];
    r.x = r.x * sA.x + sB.x;
    r.y = r.y * sA.y + sB.y;
    r.z = r.z * sA.z + sB.z;
    r.w = r.w * sA.w + sB.w;
    float4 wc0 = ((const float4*)Wc)[q * 2];
    float4 wc1 = ((const float4*)Wc)[q * 2 + 1];
    float o0 = r.x * wc0.x + r.y * wc0.z + r.z * wc1.x + r.w * wc1.z;
    float o1 = r.x * wc0.y + r.y * wc0.w + r.z * wc1.y + r.w * wc1.w;
    #pragma unroll
    for (int mask = 1; mask <= 4; mask <<= 1) {
        o0 += __shfl_xor(o0, mask);
        o1 += __shfl_xor(o1, mask);
    }
    if (lane == 0) {
        float2 ov = {o0 + bc[0], o1 + bc[1]};
        *(float2*)(out + (size_t)i * 2) = ov;
    }
}

// ---------------- launcher ----------------

extern "C" void kernel_launch(void* const* d_in, const int* in_sizes, int n_in,
                              void* d_out, int out_size, void* d_ws, size_t ws_size,
                              hipStream_t stream) {
    const float* x    = (const float*)d_in[0];
    const int*   ei   = (const int*)d_in[1];
    const float* Wl0  = (const float*)d_in[2];
    const float* Wr0  = (const float*)d_in[3];
    const float* att0 = (const float*)d_in[4];
    const float* b0   = (const float*)d_in[5];
    const float* g0   = (const float*)d_in[6];
    const float* be0  = (const float*)d_in[7];
    const float* m0   = (const float*)d_in[8];
    const float* v0   = (const float*)d_in[9];
    const float* Wl1  = (const float*)d_in[10];
    const float* Wr1  = (const float*)d_in[11];
    const float* att1 = (const float*)d_in[12];
    const float* b1   = (const float*)d_in[13];
    const float* g1   = (const float*)d_in[14];
    const float* be1  = (const float*)d_in[15];
    const float* m1   = (const float*)d_in[16];
    const float* v1   = (const float*)d_in[17];
    const float* Wc   = (const float*)d_in[18];
    const float* bc   = (const float*)d_in[19];
    float* out = (float*)d_out;

    const int N = N_NODES, E = E_EDGES;
    const int* srcp = ei;        // edge_index[0]
    const int* dstp = ei + E;    // edge_index[1]

    // workspace carve-up (16B-aligned chunks)
    char* p = (char*)d_ws;
    _Float16* xlf = (_Float16*)p; p += (size_t)M_PAD * HC * 2;   // xl table [M_PAD,256] f16
    _Float16* xrf = (_Float16*)p; p += (size_t)M_PAD * HC * 2;   // xr table [M_PAD,256] f16
    _Float16* h0  = (_Float16*)p; p += (size_t)M_PAD * HC * 2;   // h0 [M_PAD,256] f16
    _Float16* W0lt = (_Float16*)p; p += (size_t)HC * IN_CH * 2;  // Wt of Wl0 [256][128]
    _Float16* W0rt = (_Float16*)p; p += (size_t)HC * IN_CH * 2;
    _Float16* W1lt = (_Float16*)p; p += (size_t)HC * HC * 2;     // Wt of Wl1 [256][256]
    _Float16* W1rt = (_Float16*)p; p += (size_t)HC * HC * 2;
    float* sc0 = (float*)p;       p += 256 * 4;
    float* sh0 = (float*)p;       p += 256 * 4;
    float* sc1 = (float*)p;       p += 32 * 4;
    float* sh1 = (float*)p;       p += 32 * 4;
    _Float16* attl0 = (_Float16*)p; p += 256 * 2;
    _Float16* attl1 = (_Float16*)p; p += 256 * 2;
    int* deg      = (int*)p;                 // N (memset 0)
    int* done     = deg + N;                 // 4 ints (memset 0)
    int* row_ptr  = done + 4;                // N + 1
    int* cursor   = row_ptr + (N + 1);       // N
    int* partials = cursor + N;              // SCAN_B (padded 104)
    int* csr_src  = partials + 104;          // E + N entries

    // zero deg + done (graph-capture-safe)
    hipMemsetAsync(deg, 0, (size_t)(N + 4) * sizeof(int), stream);

    // weight transpose + fold tables
    k_split_w4<<<769, 256, 0, stream>>>(Wl0, Wr0, Wl1, Wr1,
                                        W0lt, W0rt, W1lt, W1rt,
                                        att0, att1,
                                        b0, g0, be0, m0, v0,
                                        b1, g1, be1, m1, v1,
                                        sc0, sh0, sc1, sh1, attl0, attl1);

    // layer 0 projections (+ fused degree histogram in y==2 blocks)
    dim3 ggrid0(M_PAD / 128, 3);
    k_gemm_mfma<<<ggrid0, 512, 0, stream>>>(nullptr, x, W0lt, W0rt, xlf, xrf,
                                            IN_CH, dstp, deg, E);

    // CSR: fused scan (local + chunk-sum) -> add (+self-loop) -> fill
    k_scan_local<<<SCAN_B, 256, 0, stream>>>(deg, row_ptr, partials, done, N);
    k_scan_add<<<(N + 255) / 256, 256, 0, stream>>>(row_ptr, cursor, csr_src,
                                                    partials, N);
    k_fill<<<(E + 255) / 256, 256, 0, stream>>>(srcp, dstp, cursor, csr_src, E);

    // layer 0 edge pass + BN + ELU -> h0 (f16)
    k_edge0<<<N / 2, 128, 0, stream>>>(xlf, xrf, attl0, row_ptr, csr_src,
                                       sc0, sh0, h0);
    // layer 1 projections: xl1 = h0@Wl1, xr1 = h0@Wr1
    dim3 ggrid1(M_PAD / 128, 2);
    k_gemm_mfma<<<ggrid1, 512, 0, stream>>>(h0, nullptr, W1lt, W1rt, xlf, xrf,
                                            HC, nullptr, nullptr, 0);
    // layer 1 edge pass + head-mean + BN + classifier -> out
    k_edge1<<<N / 2, 128, 0, stream>>>(xlf, xrf, attl1, row_ptr, csr_src,
                                       sc1, sh1, Wc, bc, out);
}

// Round 10
// 351.062 us; speedup vs baseline: 1.0824x; 1.0182x over previous
//
#include <hip/hip_runtime.h>
#include <math.h>

#define N_NODES 50000
#define M_PAD   50048    // 391 * 128
#define E_EDGES 800000
#define IN_CH   128
#define C_CH    32
#define H_HEADS 8
#define HC      256      // H_HEADS * C_CH
#define BN_EPS  1e-5f
#define SLOPE   0.2f
#define LOG2E   1.44269504f

typedef _Float16 f16x8 __attribute__((ext_vector_type(8)));
typedef _Float16 f16x4 __attribute__((ext_vector_type(4)));
typedef _Float16 f16x2 __attribute__((ext_vector_type(2)));
typedef float    f32x4 __attribute__((ext_vector_type(4)));

#if __has_builtin(__builtin_amdgcn_exp2f)
#define EXP2F(x) __builtin_amdgcn_exp2f(x)
#else
#define EXP2F(x) exp2f(x)
#endif

// ---------------- CSR build (scan-free) ----------------
// deg zero-init + ctr zero in k_split_w4 tail; hist fused into gemm0
// (y==2 blocks); segments allocated by wave-aggregated atomic bump --
// row order in csr_src is irrelevant (each wave reads only its own
// contiguous segment), so no prefix scan is needed.

__global__ __launch_bounds__(256) void k_alloc(
        const int* __restrict__ deg, int* __restrict__ ctr,
        int* __restrict__ row_beg, int* __restrict__ row_end,
        int* __restrict__ cursor, int* __restrict__ csr_src) {
    int i = blockIdx.x * blockDim.x + threadIdx.x;
    int lane = threadIdx.x & 63;
    int d = (i < N_NODES) ? deg[i] + 1 : 0;     // +1 = self-loop
    int pfx = d;                                 // 64-lane inclusive prefix
    #pragma unroll
    for (int off = 1; off < 64; off <<= 1) {
        int u = __shfl_up(pfx, off);
        if (lane >= off) pfx += u;
    }
    int total = __shfl(pfx, 63);
    int base = 0;
    if (lane == 63) base = atomicAdd(ctr, total); // one atomic per wave
    base = __shfl(base, 63);
    int p = base + pfx - d;                      // exclusive prefix
    if (i < N_NODES) {
        row_beg[i] = p;
        row_end[i] = p + d;
        cursor[i] = p + 1;                       // self-loop occupies slot p
        csr_src[p] = i << 9;                     // byte offset (node * 512)
    }
}

// csr_src stores BYTE offsets into the xl table (node * 512) so the edge
// kernels' gather address is a single v_add.
__global__ void k_fill(const int* __restrict__ src, const int* __restrict__ dst,
                       int* cursor, int* csr_src, int e) {
    int i = blockIdx.x * blockDim.x + threadIdx.x;
    if (i < e) {
        int d = dst[i];
        int p = atomicAdd(&cursor[d], 1);
        csr_src[p] = src[i] << 9;
    }
}

// ---------------- weight prep + fold tables + deg/ctr init (fused) ----------
// all 4 W [K,256] -> Wt f16 [256][K]; tail threads: BN folds, f16 att tables,
// deg[i]=0, ctr=0.

__global__ void k_split_w4(const float* __restrict__ Wl0, const float* __restrict__ Wr0,
                           const float* __restrict__ Wl1, const float* __restrict__ Wr1,
                           _Float16* __restrict__ W0lt, _Float16* __restrict__ W0rt,
                           _Float16* __restrict__ W1lt, _Float16* __restrict__ W1rt,
                           const float* __restrict__ att0, const float* __restrict__ att1,
                           const float* __restrict__ b0, const float* __restrict__ g0,
                           const float* __restrict__ be0, const float* __restrict__ m0,
                           const float* __restrict__ v0,
                           const float* __restrict__ b1, const float* __restrict__ g1,
                           const float* __restrict__ be1, const float* __restrict__ m1,
                           const float* __restrict__ v1,
                           float* __restrict__ sc0, float* __restrict__ sh0,
                           float* __restrict__ sc1, float* __restrict__ sh1,
                           _Float16* __restrict__ attl0, _Float16* __restrict__ attl1,
                           int* __restrict__ deg, int* __restrict__ ctr) {
    int t = blockIdx.x * blockDim.x + threadIdx.x;
    const float* W; _Float16* O; int K, rel;
    if (t < 32768)       { W = Wl0; O = W0lt; K = 128; rel = t; }
    else if (t < 65536)  { W = Wr0; O = W0rt; K = 128; rel = t - 32768; }
    else if (t < 131072) { W = Wl1; O = W1lt; K = 256; rel = t - 65536; }
    else if (t < 196608) { W = Wr1; O = W1rt; K = 256; rel = t - 131072; }
    else if (t < 196864) {
        int ch = t - 196608;
        float s = rsqrtf(v0[ch] + BN_EPS) * g0[ch];
        sc0[ch] = s;
        sh0[ch] = (b0[ch] - m0[ch]) * s + be0[ch];
        attl0[ch] = (_Float16)(att0[ch] * LOG2E);
        attl1[ch] = (_Float16)(att1[ch] * LOG2E);
        if (ch < 32) {
            float s1 = rsqrtf(v1[ch] + BN_EPS) * g1[ch];
            sc1[ch] = 0.125f * s1;
            sh1[ch] = (b1[ch] - m1[ch]) * s1 + be1[ch];
        }
        if (ch == 0) *ctr = 0;
        return;
    } else {
        int i = t - 196864;
        if (i < N_NODES) deg[i] = 0;
        return;
    }
    int n = rel / K, k = rel - n * K;
    O[rel] = (_Float16)W[(size_t)k * 256 + n];
}

// ---------------- f16 MFMA GEMM, z-fused: C0 = A@W0, C1 = A@W1 ----------------
// A staged ONCE per block, both B tables consumed (r1/r2: ~20us vs z-split).
// Tile: BM=128, BN=128, BK=32; 8 waves as 2m x 4n (8 ds_read per 16 MFMA).
// Reg-staged prefetch; LDS-staged coalesced epilogue (r4: -9us).
// blockIdx.y==2 blocks (layer-0 launch only) run the CSR degree histogram,
// overlapping its 800K atomics under the MFMA work.
// mfma_f32_16x16x32_f16 layouts (m89/m91-verified):
//   A: m=lane&15, k=(lane>>4)*8+j   B: n=lane&15, k=(lane>>4)*8+j
//   C/D: col=lane&15, row=(lane>>4)*4+reg

#define BK  32
#define LDA 40    // staging row pitch in f16 (32 + 8 pad -> 80 B, 16B-aligned)
#define CP  136   // C-stage pitch in f16 (272 B: 16B-aligned, quads spread banks)

__device__ __forceinline__ f16x8 cvt_h8(float4 a, float4 b) {
    f16x8 v = { (_Float16)a.x, (_Float16)a.y, (_Float16)a.z, (_Float16)a.w,
                (_Float16)b.x, (_Float16)b.y, (_Float16)b.z, (_Float16)b.w };
    return v;
}

__global__ __launch_bounds__(512) void k_gemm_mfma(
        const _Float16* __restrict__ A16, const float* __restrict__ A32,
        const _Float16* __restrict__ W0t, const _Float16* __restrict__ W1t,
        _Float16* __restrict__ C0, _Float16* __restrict__ C1, int K,
        const int* __restrict__ hdst, int* __restrict__ hdeg, int he) {
    if (blockIdx.y == 2) {              // fused degree histogram (layer 0 only)
        int tid = blockIdx.x * blockDim.x + threadIdx.x;
        int stride = gridDim.x * blockDim.x;
        for (int i = tid; i < he; i += stride)
            atomicAdd(&hdeg[hdst[i]], 1);
        return;
    }
    __shared__ _Float16 smem[128 * CP];   // 34816 B; aliases staging + C-stage
    _Float16* As  = smem;                 // 128*40 = 5120
    _Float16* Bs0 = smem + 5120;
    _Float16* Bs1 = smem + 10240;         // staging total 15360 <= 17408
    int t = threadIdx.x;
    int lane = t & 63, wv = t >> 6;           // 8 waves
    int quad = lane >> 4, r16 = lane & 15;
    int wm = wv >> 2;             // 0..1 -> row base wm*64
    int wn = wv & 3;              // 0..3 -> col base wn*32
    size_t mBase = (size_t)blockIdx.x * 128;
    size_t nBase = (size_t)blockIdx.y * 128;
    int sr = t >> 2;              // staging row 0..127
    int sc = (t & 3) * 8;         // staging col (f16 units)
    size_t rA = mBase + sr;
    const bool aValid = rA < N_NODES;
    f32x4 acc0[4][2] = {}, acc1[4][2] = {};   // [mi][ni]
    // prologue: load k0 = 0 into registers
    f16x8 pa, pb0, pb1;
    if (A32) {
        float4 a0 = {0.f, 0.f, 0.f, 0.f}, a1 = a0;
        if (aValid) {
            const float* g = A32 + rA * K + sc;
            a0 = ((const float4*)g)[0];
            a1 = ((const float4*)g)[1];
        }
        pa = cvt_h8(a0, a1);
    } else {
        pa = *(const f16x8*)(A16 + rA * K + sc);
    }
    pb0 = *(const f16x8*)(W0t + (size_t)(nBase + sr) * K + sc);
    pb1 = *(const f16x8*)(W1t + (size_t)(nBase + sr) * K + sc);
    for (int k0 = 0; k0 < K; k0 += BK) {
        *(f16x8*)&As[sr * LDA + sc]  = pa;
        *(f16x8*)&Bs0[sr * LDA + sc] = pb0;
        *(f16x8*)&Bs1[sr * LDA + sc] = pb1;
        __syncthreads();
        int kn = k0 + BK;
        if (kn < K) {                 // prefetch next tile (uniform branch)
            if (A32) {
                float4 a0 = {0.f, 0.f, 0.f, 0.f}, a1 = a0;
                if (aValid) {
                    const float* g = A32 + rA * K + kn + sc;
                    a0 = ((const float4*)g)[0];
                    a1 = ((const float4*)g)[1];
                }
                pa = cvt_h8(a0, a1);
            } else {
                pa = *(const f16x8*)(A16 + rA * K + kn + sc);
            }
            pb0 = *(const f16x8*)(W0t + (size_t)(nBase + sr) * K + kn + sc);
            pb1 = *(const f16x8*)(W1t + (size_t)(nBase + sr) * K + kn + sc);
        }
        f16x8 av[4];
        #pragma unroll
        for (int mi = 0; mi < 4; ++mi)
            av[mi] = *(f16x8*)&As[(wm * 64 + mi * 16 + r16) * LDA + quad * 8];
        #pragma unroll
        for (int ni = 0; ni < 2; ++ni) {
            f16x8 bv0 = *(f16x8*)&Bs0[(wn * 32 + ni * 16 + r16) * LDA + quad * 8];
            f16x8 bv1 = *(f16x8*)&Bs1[(wn * 32 + ni * 16 + r16) * LDA + quad * 8];
            #pragma unroll
            for (int mi = 0; mi < 4; ++mi) {
                acc0[mi][ni] = __builtin_amdgcn_mfma_f32_16x16x32_f16(av[mi], bv0, acc0[mi][ni], 0, 0, 0);
                acc1[mi][ni] = __builtin_amdgcn_mfma_f32_16x16x32_f16(av[mi], bv1, acc1[mi][ni], 0, 0, 0);
            }
        }
        __syncthreads();
    }
    // epilogue: LDS-stage each C tile, then coalesced f16x8 stores.
    int erow = t >> 2;            // 0..127
    int ec = (t & 3) * 8;         // lane-contiguous 64 B chunks across (t&3)
    size_t obase = (mBase + erow) * 256 + nBase + ec;
    #pragma unroll
    for (int tab = 0; tab < 2; ++tab) {
        __syncthreads();
        #pragma unroll
        for (int mi = 0; mi < 4; ++mi)
            #pragma unroll
            for (int ni = 0; ni < 2; ++ni)
                #pragma unroll
                for (int r = 0; r < 4; ++r) {
                    float v = tab ? acc1[mi][ni][r] : acc0[mi][ni][r];
                    smem[(wm * 64 + mi * 16 + quad * 4 + r) * CP + wn * 32 + ni * 16 + r16]
                        = (_Float16)v;
                }
        __syncthreads();
        f16x8 v0 = *(const f16x8*)&smem[erow * CP + ec];
        f16x8 v1 = *(const f16x8*)&smem[erow * CP + ec + 32];
        f16x8 v2 = *(const f16x8*)&smem[erow * CP + ec + 64];
        f16x8 v3 = *(const f16x8*)&smem[erow * CP + ec + 96];
        _Float16* C = tab ? C1 : C0;
        *(f16x8*)(C + obase)      = v0;
        *(f16x8*)(C + obase + 32) = v1;
        *(f16x8*)(C + obase + 64) = v2;
        *(f16x8*)(C + obase + 96) = v3;
    }
}

// ---------------- edge pass: one wave per node, 4 channels per lane ----------------
// r8 skeleton (8 + 4 + scalar edge chains, slim setup). Logit reduce is now
// ALL-DPP: xor1, xor2 quad_perm + row_half_mirror for the cross-quad add
// (after xor1+xor2 each quad is uniform, so half-mirror reads the other quad)
// -- no LDS-pipe op left in the per-edge chain.

__device__ __forceinline__ float qreduce8(float p) {
    p += __builtin_bit_cast(float, __builtin_amdgcn_mov_dpp(
             __builtin_bit_cast(int, p), 0xB1, 0xF, 0xF, true));   // quad_perm [1,0,3,2]
    p += __builtin_bit_cast(float, __builtin_amdgcn_mov_dpp(
             __builtin_bit_cast(int, p), 0x4E, 0xF, 0xF, true));   // quad_perm [2,3,0,1]
    p += __builtin_bit_cast(float, __builtin_amdgcn_mov_dpp(
             __builtin_bit_cast(int, p), 0x141, 0xF, 0xF, true));  // row_half_mirror
    return p;
}

__device__ __forceinline__ float edge_w16(f16x4 h, f16x4 xr, f16x4 att) {
    f16x4 e = h + xr;                                    // 2x v_pk_add_f16
    f16x4 es = e * (_Float16)SLOPE;                      // 2x v_pk_mul_f16
    f16x4 l = __builtin_elementwise_max(e, es);          // 2x v_pk_max_f16 (slope<1)
#if __has_builtin(__builtin_amdgcn_fdot2)
    f16x2 l01 = __builtin_shufflevector(l, l, 0, 1);
    f16x2 l23 = __builtin_shufflevector(l, l, 2, 3);
    f16x2 a01 = __builtin_shufflevector(att, att, 0, 1);
    f16x2 a23 = __builtin_shufflevector(att, att, 2, 3);
    float p = __builtin_amdgcn_fdot2(l01, a01, 0.f, false);
    p = __builtin_amdgcn_fdot2(l23, a23, p, false);
#else
    float p = (float)l[0] * (float)att[0];
    p = fmaf((float)l[1], (float)att[1], p);
    p = fmaf((float)l[2], (float)att[2], p);
    p = fmaf((float)l[3], (float)att[3], p);
#endif
    return EXP2F(qreduce8(p));         // att carries log2(e)
}

__device__ __forceinline__ void acc1e(float4& acc, f16x4 h, float w) {
    acc.x = fmaf((float)h[0], w, acc.x); acc.y = fmaf((float)h[1], w, acc.y);
    acc.z = fmaf((float)h[2], w, acc.z); acc.w = fmaf((float)h[3], w, acc.w);
}

__device__ __forceinline__ float4 edge_accum(
        const char* __restrict__ xlb, f16x4 xr_h, f16x4 att_h,
        const int* __restrict__ csr_src, int beg, int end) {
    float4 acc = {0.f, 0.f, 0.f, 0.f};
    float S = 0.f;
    int j = beg;
    for (; j + 8 <= end; j += 8) {
        int o0 = csr_src[j];     int o1 = csr_src[j + 1];
        int o2 = csr_src[j + 2]; int o3 = csr_src[j + 3];
        int o4 = csr_src[j + 4]; int o5 = csr_src[j + 5];
        int o6 = csr_src[j + 6]; int o7 = csr_src[j + 7];
        f16x4 h0 = *(const f16x4*)(xlb + o0);
        f16x4 h1 = *(const f16x4*)(xlb + o1);
        f16x4 h2 = *(const f16x4*)(xlb + o2);
        f16x4 h3 = *(const f16x4*)(xlb + o3);
        f16x4 h4 = *(const f16x4*)(xlb + o4);
        f16x4 h5 = *(const f16x4*)(xlb + o5);
        f16x4 h6 = *(const f16x4*)(xlb + o6);
        f16x4 h7 = *(const f16x4*)(xlb + o7);
        float w0 = edge_w16(h0, xr_h, att_h);
        float w1 = edge_w16(h1, xr_h, att_h);
        float w2 = edge_w16(h2, xr_h, att_h);
        float w3 = edge_w16(h3, xr_h, att_h);
        float w4 = edge_w16(h4, xr_h, att_h);
        float w5 = edge_w16(h5, xr_h, att_h);
        float w6 = edge_w16(h6, xr_h, att_h);
        float w7 = edge_w16(h7, xr_h, att_h);
        S += ((w0 + w1) + (w2 + w3)) + ((w4 + w5) + (w6 + w7));
        acc1e(acc, h0, w0); acc1e(acc, h1, w1);
        acc1e(acc, h2, w2); acc1e(acc, h3, w3);
        acc1e(acc, h4, w4); acc1e(acc, h5, w5);
        acc1e(acc, h6, w6); acc1e(acc, h7, w7);
    }
    for (; j + 4 <= end; j += 4) {
        int o0 = csr_src[j];     int o1 = csr_src[j + 1];
        int o2 = csr_src[j + 2]; int o3 = csr_src[j + 3];
        f16x4 h0 = *(const f16x4*)(xlb + o0);
        f16x4 h1 = *(const f16x4*)(xlb + o1);
        f16x4 h2 = *(const f16x4*)(xlb + o2);
        f16x4 h3 = *(const f16x4*)(xlb + o3);
        float w0 = edge_w16(h0, xr_h, att_h);
        float w1 = edge_w16(h1, xr_h, att_h);
        float w2 = edge_w16(h2, xr_h, att_h);
        float w3 = edge_w16(h3, xr_h, att_h);
        S += (w0 + w1) + (w2 + w3);
        acc1e(acc, h0, w0); acc1e(acc, h1, w1);
        acc1e(acc, h2, w2); acc1e(acc, h3, w3);
    }
    for (; j < end; ++j) {
        int o = csr_src[j];
        f16x4 hv = *(const f16x4*)(xlb + o);
        float w = edge_w16(hv, xr_h, att_h);
        S += w;
        acc1e(acc, hv, w);
    }
    float inv = 1.f / S;
    acc.x *= inv; acc.y *= inv; acc.z *= inv; acc.w *= inv;
    return acc;
}

// layer 0: concat + folded BN + ELU -> h0 (f16).
__global__ __launch_bounds__(128) void k_edge0(
        const _Float16* __restrict__ xl, const _Float16* __restrict__ xr,
        const _Float16* __restrict__ attl,
        const int* __restrict__ row_beg, const int* __restrict__ row_end,
        const int* __restrict__ csr_src,
        const float* __restrict__ sc0, const float* __restrict__ sh0,
        _Float16* __restrict__ h0) {
    int lane = threadIdx.x & 63;
    int i = __builtin_amdgcn_readfirstlane(blockIdx.x * 2 + (threadIdx.x >> 6));
    const char* xlb = (const char*)xl + lane * 8;    // 8 B/lane within each 512 B row
    f16x4 xr_h = ((const f16x4*)xr)[(size_t)i * 64 + lane];
    f16x4 att_h = ((const f16x4*)attl)[lane];
    int beg = row_beg[i], end = row_end[i];
    float4 r = edge_accum(xlb, xr_h, att_h, csr_src, beg, end);
    float4 sc = ((const float4*)sc0)[lane];
    float4 sh = ((const float4*)sh0)[lane];
    float4 o;
    o.x = r.x * sc.x + sh.x;
    o.y = r.y * sc.y + sh.y;
    o.z = r.z * sc.z + sh.z;
    o.w = r.w * sc.w + sh.w;
    o.x = o.x > 0.f ? o.x : expm1f(o.x);
    o.y = o.y > 0.f ? o.y : expm1f(o.y);
    o.z = o.z > 0.f ? o.z : expm1f(o.z);
    o.w = o.w > 0.f ? o.w : expm1f(o.w);
    f16x4 hh = { (_Float16)o.x, (_Float16)o.y, (_Float16)o.z, (_Float16)o.w };
    ((f16x4*)h0)[(size_t)i * 64 + lane] = hh;
}

// layer 1: head-mean + folded BN + classifier, fully in-register.
__global__ __launch_bounds__(128) void k_edge1(
        const _Float16* __restrict__ xl, const _Float16* __restrict__ xr,
        const _Float16* __restrict__ attl,
        const int* __restrict__ row_beg, const int* __restrict__ row_end,
        const int* __restrict__ csr_src,
        const float* __restrict__ sc1, const float* __restrict__ sh1,
        const float* __restrict__ Wc, const float* __restrict__ bc,
        float* __restrict__ out) {
    int lane = threadIdx.x & 63;
    int q = lane & 7;
    int i = __builtin_amdgcn_readfirstlane(blockIdx.x * 2 + (threadIdx.x >> 6));
    const char* xlb = (const char*)xl + lane * 8;
    f16x4 xr_h = ((const f16x4*)xr)[(size_t)i * 64 + lane];
    f16x4 att_h = ((const f16x4*)attl)[lane];
    int beg = row_beg[i], end = row_end[i];
    float4 r = edge_accum(xlb, xr_h, att_h, csr_src, beg, end);
    #pragma unroll
    for (int mask = 8; mask <= 32; mask <<= 1) {
        r.x += __shfl_xor(r.x, mask);
        r.y += __shfl_xor(r.y, mask);
        r.z += __shfl_xor(r.z, mask);
        r.w += __shfl_xor(r.w, mask);
    }
    float4 sA = ((const float4*)sc1)[q];   // 0.125 * rsqrt * g
    float4 sB = ((const float4*)sh1)[q];
    r.x = r.x * sA.x + sB.x;
    r.y = r.y * sA.y + sB.y;
    r.z = r.z * sA.z + sB.z;
    r.w = r.w * sA.w + sB.w;
    float4 wc0 = ((const float4*)Wc)[q * 2];
    float4 wc1 = ((const float4*)Wc)[q * 2 + 1];
    float o0 = r.x * wc0.x + r.y * wc0.z + r.z * wc1.x + r.w * wc1.z;
    float o1 = r.x * wc0.y + r.y * wc0.w + r.z * wc1.y + r.w * wc1.w;
    #pragma unroll
    for (int mask = 1; mask <= 4; mask <<= 1) {
        o0 += __shfl_xor(o0, mask);
        o1 += __shfl_xor(o1, mask);
    }
    if (lane == 0) {
        float2 ov = {o0 + bc[0], o1 + bc[1]};
        *(float2*)(out + (size_t)i * 2) = ov;
    }
}

// ---------------- launcher ----------------

extern "C" void kernel_launch(void* const* d_in, const int* in_sizes, int n_in,
                              void* d_out, int out_size, void* d_ws, size_t ws_size,
                              hipStream_t stream) {
    const float* x    = (const float*)d_in[0];
    const int*   ei   = (const int*)d_in[1];
    const float* Wl0  = (const float*)d_in[2];
    const float* Wr0  = (const float*)d_in[3];
    const float* att0 = (const float*)d_in[4];
    const float* b0   = (const float*)d_in[5];
    const float* g0   = (const float*)d_in[6];
    const float* be0  = (const float*)d_in[7];
    const float* m0   = (const float*)d_in[8];
    const float* v0   = (const float*)d_in[9];
    const float* Wl1  = (const float*)d_in[10];
    const float* Wr1  = (const float*)d_in[11];
    const float* att1 = (const float*)d_in[12];
    const float* b1   = (const float*)d_in[13];
    const float* g1   = (const float*)d_in[14];
    const float* be1  = (const float*)d_in[15];
    const float* m1   = (const float*)d_in[16];
    const float* v1   = (const float*)d_in[17];
    const float* Wc   = (const float*)d_in[18];
    const float* bc   = (const float*)d_in[19];
    float* out = (float*)d_out;

    const int N = N_NODES, E = E_EDGES;
    const int* srcp = ei;        // edge_index[0]
    const int* dstp = ei + E;    // edge_index[1]

    // workspace carve-up (16B-aligned chunks)
    char* p = (char*)d_ws;
    _Float16* xlf = (_Float16*)p; p += (size_t)M_PAD * HC * 2;   // xl table [M_PAD,256] f16
    _Float16* xrf = (_Float16*)p; p += (size_t)M_PAD * HC * 2;   // xr table [M_PAD,256] f16
    _Float16* h0  = (_Float16*)p; p += (size_t)M_PAD * HC * 2;   // h0 [M_PAD,256] f16
    _Float16* W0lt = (_Float16*)p; p += (size_t)HC * IN_CH * 2;  // Wt of Wl0 [256][128]
    _Float16* W0rt = (_Float16*)p; p += (size_t)HC * IN_CH * 2;
    _Float16* W1lt = (_Float16*)p; p += (size_t)HC * HC * 2;     // Wt of Wl1 [256][256]
    _Float16* W1rt = (_Float16*)p; p += (size_t)HC * HC * 2;
    float* sc0 = (float*)p;       p += 256 * 4;
    float* sh0 = (float*)p;       p += 256 * 4;
    float* sc1 = (float*)p;       p += 32 * 4;
    float* sh1 = (float*)p;       p += 32 * 4;
    _Float16* attl0 = (_Float16*)p; p += 256 * 2;
    _Float16* attl1 = (_Float16*)p; p += 256 * 2;
    int* deg      = (int*)p;                 // N
    int* ctr      = deg + N;                 // 4 ints
    int* row_beg  = ctr + 4;                 // N
    int* row_end  = row_beg + N;             // N
    int* cursor   = row_end + N;             // N
    int* csr_src  = cursor + N;              // E + N entries

    // weight transpose + fold tables + deg/ctr zero (one launch)
    k_split_w4<<<965, 256, 0, stream>>>(Wl0, Wr0, Wl1, Wr1,
                                        W0lt, W0rt, W1lt, W1rt,
                                        att0, att1,
                                        b0, g0, be0, m0, v0,
                                        b1, g1, be1, m1, v1,
                                        sc0, sh0, sc1, sh1, attl0, attl1,
                                        deg, ctr);

    // layer 0 projections (+ fused degree histogram in y==2 blocks)
    dim3 ggrid0(M_PAD / 128, 3);
    k_gemm_mfma<<<ggrid0, 512, 0, stream>>>(nullptr, x, W0lt, W0rt, xlf, xrf,
                                            IN_CH, dstp, deg, E);

    // CSR: wave-aggregated atomic segment alloc (+self-loop) -> fill
    k_alloc<<<(N + 255) / 256, 256, 0, stream>>>(deg, ctr, row_beg, row_end,
                                                 cursor, csr_src);
    k_fill<<<(E + 255) / 256, 256, 0, stream>>>(srcp, dstp, cursor, csr_src, E);

    // layer 0 edge pass + BN + ELU -> h0 (f16)
    k_edge0<<<N / 2, 128, 0, stream>>>(xlf, xrf, attl0, row_beg, row_end,
                                       csr_src, sc0, sh0, h0);
    // layer 1 projections: xl1 = h0@Wl1, xr1 = h0@Wr1
    dim3 ggrid1(M_PAD / 128, 2);
    k_gemm_mfma<<<ggrid1, 512, 0, stream>>>(h0, nullptr, W1lt, W1rt, xlf, xrf,
                                            HC, nullptr, nullptr, 0);
    // layer 1 edge pass + head-mean + BN + classifier -> out
    k_edge1<<<N / 2, 128, 0, stream>>>(xlf, xrf, attl1, row_beg, row_end,
                                       csr_src, sc1, sh1, Wc, bc, out);
}